// Round 1
// baseline (55.978 us; speedup 1.0000x reference)
//
#include <hip/hip_runtime.h>
#include <hip/hip_bf16.h>

#define MDIM 16384
#define NDIM 1024
#define KDIM 512
#define BM 128
#define BN 128
#define BK 64

typedef __attribute__((ext_vector_type(8))) short bf16x8;
typedef __attribute__((ext_vector_type(4))) float f32x4;

__device__ __forceinline__ short f2bf(float f) {
    union { float f; unsigned u; } v; v.f = f;
    unsigned r = v.u + 0x7fff + ((v.u >> 16) & 1);   // RNE truncate to bf16
    return (short)(r >> 16);
}

__device__ __forceinline__ bf16x8 cvt8(float4 a, float4 b) {
    bf16x8 o;
    o[0] = f2bf(a.x); o[1] = f2bf(a.y); o[2] = f2bf(a.z); o[3] = f2bf(a.w);
    o[4] = f2bf(b.x); o[5] = f2bf(b.y); o[6] = f2bf(b.z); o[7] = f2bf(b.w);
    return o;
}

// One wave per row: sum of squares for X (16384 rows) and P (1024 rows).
__global__ __launch_bounds__(256) void sumsq_kernel(
        const float* __restrict__ X, const float* __restrict__ P,
        float* __restrict__ xsq, float* __restrict__ psq) {
    int wave = (blockIdx.x * blockDim.x + threadIdx.x) >> 6;
    int lane = threadIdx.x & 63;
    const float* src; float* dst; int row;
    if (wave < MDIM) { src = X; dst = xsq; row = wave; }
    else             { src = P; dst = psq; row = wave - MDIM; }
    const float4* r4 = (const float4*)(src + (size_t)row * KDIM) + lane * 2;
    float4 a = r4[0], b = r4[1];
    float s = a.x*a.x + a.y*a.y + a.z*a.z + a.w*a.w
            + b.x*b.x + b.y*b.y + b.z*b.z + b.w*b.w;
    #pragma unroll
    for (int off = 32; off; off >>= 1) s += __shfl_down(s, off, 64);
    if (lane == 0) dst[row] = s;
}

// 128x128 tile GEMM: out[b,p] = 2*(X.P^T)[b,p] - xsq[b] - psq[p]
__global__ __launch_bounds__(256) void dist_gemm(
        const float* __restrict__ X, const float* __restrict__ P,
        const float* __restrict__ xsq, const float* __restrict__ psq,
        float* __restrict__ out) {
    __shared__ short As[BM * BK];
    __shared__ short Bs[BN * BK];

    int tid = threadIdx.x;
    int bid = blockIdx.x;
    // bijective XCD swizzle: nwg = 1024, 8 XCDs -> chunks of 128
    int swz = (bid & 7) * 128 + (bid >> 3);
    int bn = swz & 7, bm = swz >> 3;
    int row0 = bm * BM, col0 = bn * BN;

    int lane = tid & 63, wid = tid >> 6;
    int wm = (wid >> 1) * 64, wn = (wid & 1) * 64;  // 2x2 wave grid

    f32x4 acc[4][4] = {};

    int rbase = tid >> 3;      // 0..31 (tile row base for staging)
    int kg = tid & 7;          // k-group (8 bf16 each)
    const float* Abase = X + (size_t)row0 * KDIM;
    const float* Bbase = P + (size_t)col0 * KDIM;

    for (int kt = 0; kt < KDIM / BK; ++kt) {
        int kofs = kt * BK + kg * 8;
        __syncthreads();
        #pragma unroll
        for (int i = 0; i < 4; ++i) {
            int row = rbase + 32 * i;
            const float4* ga = (const float4*)(Abase + (size_t)row * KDIM + kofs);
            float4 a0 = ga[0], a1 = ga[1];
            const float4* gb = (const float4*)(Bbase + (size_t)row * KDIM + kofs);
            float4 b0 = gb[0], b1 = gb[1];
            int off = (row * (BK * 2) + kg * 16) ^ ((row & 7) << 4);  // T2 swizzle
            *(bf16x8*)((char*)As + off) = cvt8(a0, a1);
            *(bf16x8*)((char*)Bs + off) = cvt8(b0, b1);
        }
        __syncthreads();
        #pragma unroll
        for (int ks = 0; ks < 2; ++ks) {
            bf16x8 af[4], bfr[4];
            int kb = ks * 64 + ((lane >> 4) * 16);  // byte offset of lane's k-slice
            #pragma unroll
            for (int m = 0; m < 4; ++m) {
                int row = wm + m * 16 + (lane & 15);
                int off = (row * (BK * 2) + kb) ^ ((row & 7) << 4);
                af[m] = *(const bf16x8*)((const char*)As + off);
            }
            #pragma unroll
            for (int n = 0; n < 4; ++n) {
                int row = wn + n * 16 + (lane & 15);
                int off = (row * (BK * 2) + kb) ^ ((row & 7) << 4);
                bfr[n] = *(const bf16x8*)((const char*)Bs + off);
            }
            #pragma unroll
            for (int m = 0; m < 4; ++m)
                #pragma unroll
                for (int n = 0; n < 4; ++n)
                    acc[m][n] = __builtin_amdgcn_mfma_f32_16x16x32_bf16(
                        af[m], bfr[n], acc[m][n], 0, 0, 0);
        }
    }

    // epilogue: C/D layout col = lane&15, row = (lane>>4)*4 + reg  [m89]
    int cr = (lane >> 4) * 4;
    int cc = lane & 15;
    #pragma unroll
    for (int n = 0; n < 4; ++n) {
        int gc = col0 + wn + n * 16 + cc;
        float ps = psq[gc];
        #pragma unroll
        for (int m = 0; m < 4; ++m) {
            int grb = row0 + wm + m * 16 + cr;
            #pragma unroll
            for (int r = 0; r < 4; ++r) {
                float v = 2.0f * acc[m][n][r] - xsq[grb + r] - ps;
                out[(size_t)(grb + r) * NDIM + gc] = v;
            }
        }
    }
}

extern "C" void kernel_launch(void* const* d_in, const int* in_sizes, int n_in,
                              void* d_out, int out_size, void* d_ws, size_t ws_size,
                              hipStream_t stream) {
    const float* X = (const float*)d_in[0];
    const float* P = (const float*)d_in[1];
    float* out = (float*)d_out;
    float* xsq = (float*)d_ws;           // 16384 floats
    float* psq = xsq + MDIM;             // 1024 floats  (needs 69,632 B of ws)

    sumsq_kernel<<<(MDIM + NDIM) / 4, 256, 0, stream>>>(X, P, xsq, psq);
    dist_gemm<<<(MDIM / BM) * (NDIM / BN), 256, 0, stream>>>(X, P, xsq, psq, out);
}

// Round 2
// 44.894 us; speedup vs baseline: 1.2469x; 1.2469x over previous
//
#include <hip/hip_runtime.h>
#include <hip/hip_bf16.h>

#define MDIM 16384
#define NDIM 1024
#define KDIM 512
#define BM 128
#define BN 128
#define BK 64

typedef __attribute__((ext_vector_type(8))) short bf16x8;
typedef __attribute__((ext_vector_type(4))) float f32x4;

__device__ __forceinline__ short f2bf(float f) {
    union { float f; unsigned u; } v; v.f = f;
    unsigned r = v.u + 0x7fff + ((v.u >> 16) & 1);   // RNE truncate to bf16
    return (short)(r >> 16);
}

__device__ __forceinline__ bf16x8 cvt8(float4 a, float4 b) {
    bf16x8 o;
    o[0] = f2bf(a.x); o[1] = f2bf(a.y); o[2] = f2bf(a.z); o[3] = f2bf(a.w);
    o[4] = f2bf(b.x); o[5] = f2bf(b.y); o[6] = f2bf(b.z); o[7] = f2bf(b.w);
    return o;
}

__device__ __forceinline__ void gload_lds16(const void* g, void* l) {
    __builtin_amdgcn_global_load_lds(
        (const __attribute__((address_space(1))) void*)g,
        (__attribute__((address_space(3))) void*)l, 16, 0, 0);
}

// ---------- fast path: fused fp32->bf16 convert + sum-of-squares ----------
// one wave per row (X rows then P rows)
__global__ __launch_bounds__(256) void convert_sumsq(
        const float* __restrict__ X, const float* __restrict__ P,
        short* __restrict__ Xbf, short* __restrict__ Pbf,
        float* __restrict__ xsq, float* __restrict__ psq) {
    int wave = (blockIdx.x * blockDim.x + threadIdx.x) >> 6;
    int lane = threadIdx.x & 63;
    const float* src; short* dstb; float* dsts; int row;
    if (wave < MDIM) { src = X; dstb = Xbf; dsts = xsq; row = wave; }
    else             { src = P; dstb = Pbf; dsts = psq; row = wave - MDIM; }
    const float4* r4 = (const float4*)(src + (size_t)row * KDIM) + lane * 2;
    float4 a = r4[0], b = r4[1];
    *(bf16x8*)(dstb + (size_t)row * KDIM + lane * 8) = cvt8(a, b);
    float s = a.x*a.x + a.y*a.y + a.z*a.z + a.w*a.w
            + b.x*b.x + b.y*b.y + b.z*b.z + b.w*b.w;
    #pragma unroll
    for (int off = 32; off; off >>= 1) s += __shfl_down(s, off, 64);
    if (lane == 0) dsts[row] = s;
}

// ---------- fast path: bf16 GEMM, m97 structure (global_load_lds w16) ----------
// LDS content carries the XOR swizzle via pre-permuted global source (rule #21:
// linear dest + inverse-swizzled source + swizzled read).
__global__ __launch_bounds__(256) void dist_gemm_bf(
        const short* __restrict__ Xbf, const short* __restrict__ Pbf,
        const float* __restrict__ xsq, const float* __restrict__ psq,
        float* __restrict__ out) {
    __shared__ short As[BM * BK];   // 16 KB
    __shared__ short Bs[BN * BK];   // 16 KB

    int tid = threadIdx.x;
    int bid = blockIdx.x;
    // bijective XCD swizzle: nwg = 1024 (divisible by 8)
    int swz = (bid & 7) * 128 + (bid >> 3);
    int bn = swz & 7, bm = swz >> 3;
    int row0 = bm * BM, col0 = bn * BN;

    int lane = tid & 63, wid = tid >> 6;
    int wm = (wid >> 1) * 64, wn = (wid & 1) * 64;  // 2x2 wave grid

    f32x4 acc[4][4] = {};

    const short* Ab = Xbf + (size_t)row0 * KDIM;
    const short* Bb = Pbf + (size_t)col0 * KDIM;

    for (int kt = 0; kt < KDIM / BK; ++kt) {
        __syncthreads();            // previous iter's ds_reads done
        // stage A,B tiles: chunk c = tid + 256*i -> LDS byte c*16 (linear);
        // global slot pre-XORed so that swizzled read below sees true data
        #pragma unroll
        for (int i = 0; i < 4; ++i) {
            int c = tid + 256 * i;
            int row = c >> 3;
            int g16 = (c & 7) ^ (row & 7);
            const char* ga = (const char*)(Ab + (size_t)row * KDIM)
                             + kt * (BK * 2) + g16 * 16;
            const char* gb = (const char*)(Bb + (size_t)row * KDIM)
                             + kt * (BK * 2) + g16 * 16;
            char* la = (char*)As + i * 4096 + wid * 1024;  // wave-uniform base
            char* lb = (char*)Bs + i * 4096 + wid * 1024;
            gload_lds16(ga, la);
            gload_lds16(gb, lb);
        }
        __syncthreads();            // barrier drains vmcnt -> tiles resident
        #pragma unroll
        for (int ks = 0; ks < 2; ++ks) {
            bf16x8 af[4], bfr[4];
            int kb = ks * 64 + ((lane >> 4) * 16);
            #pragma unroll
            for (int m = 0; m < 4; ++m) {
                int row = wm + m * 16 + (lane & 15);
                int off = (row * (BK * 2) + kb) ^ ((row & 7) << 4);
                af[m] = *(const bf16x8*)((const char*)As + off);
            }
            #pragma unroll
            for (int n = 0; n < 4; ++n) {
                int row = wn + n * 16 + (lane & 15);
                int off = (row * (BK * 2) + kb) ^ ((row & 7) << 4);
                bfr[n] = *(const bf16x8*)((const char*)Bs + off);
            }
            #pragma unroll
            for (int m = 0; m < 4; ++m)
                #pragma unroll
                for (int n = 0; n < 4; ++n)
                    acc[m][n] = __builtin_amdgcn_mfma_f32_16x16x32_bf16(
                        af[m], bfr[n], acc[m][n], 0, 0, 0);
        }
    }

    // epilogue: C/D layout col = lane&15, row = (lane>>4)*4 + reg  [m89]
    int cr = (lane >> 4) * 4;
    int cc = lane & 15;
    #pragma unroll
    for (int n = 0; n < 4; ++n) {
        int gc = col0 + wn + n * 16 + cc;
        float ps = psq[gc];
        #pragma unroll
        for (int m = 0; m < 4; ++m) {
            int grb = row0 + wm + m * 16 + cr;
            #pragma unroll
            for (int r = 0; r < 4; ++r) {
                float v = 2.0f * acc[m][n][r] - xsq[grb + r] - ps;
                out[(size_t)(grb + r) * NDIM + gc] = v;
            }
        }
    }
}

// ---------- fallback path (round-1 kernels, used if ws too small) ----------
__global__ __launch_bounds__(256) void sumsq_kernel(
        const float* __restrict__ X, const float* __restrict__ P,
        float* __restrict__ xsq, float* __restrict__ psq) {
    int wave = (blockIdx.x * blockDim.x + threadIdx.x) >> 6;
    int lane = threadIdx.x & 63;
    const float* src; float* dst; int row;
    if (wave < MDIM) { src = X; dst = xsq; row = wave; }
    else             { src = P; dst = psq; row = wave - MDIM; }
    const float4* r4 = (const float4*)(src + (size_t)row * KDIM) + lane * 2;
    float4 a = r4[0], b = r4[1];
    float s = a.x*a.x + a.y*a.y + a.z*a.z + a.w*a.w
            + b.x*b.x + b.y*b.y + b.z*b.z + b.w*b.w;
    #pragma unroll
    for (int off = 32; off; off >>= 1) s += __shfl_down(s, off, 64);
    if (lane == 0) dst[row] = s;
}

__global__ __launch_bounds__(256) void dist_gemm(
        const float* __restrict__ X, const float* __restrict__ P,
        const float* __restrict__ xsq, const float* __restrict__ psq,
        float* __restrict__ out) {
    __shared__ short As[BM * BK];
    __shared__ short Bs[BN * BK];
    int tid = threadIdx.x;
    int bid = blockIdx.x;
    int swz = (bid & 7) * 128 + (bid >> 3);
    int bn = swz & 7, bm = swz >> 3;
    int row0 = bm * BM, col0 = bn * BN;
    int lane = tid & 63, wid = tid >> 6;
    int wm = (wid >> 1) * 64, wn = (wid & 1) * 64;
    f32x4 acc[4][4] = {};
    int rbase = tid >> 3;
    int kg = tid & 7;
    const float* Abase = X + (size_t)row0 * KDIM;
    const float* Bbase = P + (size_t)col0 * KDIM;
    for (int kt = 0; kt < KDIM / BK; ++kt) {
        int kofs = kt * BK + kg * 8;
        __syncthreads();
        #pragma unroll
        for (int i = 0; i < 4; ++i) {
            int row = rbase + 32 * i;
            const float4* ga = (const float4*)(Abase + (size_t)row * KDIM + kofs);
            float4 a0 = ga[0], a1 = ga[1];
            const float4* gb = (const float4*)(Bbase + (size_t)row * KDIM + kofs);
            float4 b0 = gb[0], b1 = gb[1];
            int off = (row * (BK * 2) + kg * 16) ^ ((row & 7) << 4);
            *(bf16x8*)((char*)As + off) = cvt8(a0, a1);
            *(bf16x8*)((char*)Bs + off) = cvt8(b0, b1);
        }
        __syncthreads();
        #pragma unroll
        for (int ks = 0; ks < 2; ++ks) {
            bf16x8 af[4], bfr[4];
            int kb = ks * 64 + ((lane >> 4) * 16);
            #pragma unroll
            for (int m = 0; m < 4; ++m) {
                int row = wm + m * 16 + (lane & 15);
                int off = (row * (BK * 2) + kb) ^ ((row & 7) << 4);
                af[m] = *(const bf16x8*)((const char*)As + off);
            }
            #pragma unroll
            for (int n = 0; n < 4; ++n) {
                int row = wn + n * 16 + (lane & 15);
                int off = (row * (BK * 2) + kb) ^ ((row & 7) << 4);
                bfr[n] = *(const bf16x8*)((const char*)Bs + off);
            }
            #pragma unroll
            for (int m = 0; m < 4; ++m)
                #pragma unroll
                for (int n = 0; n < 4; ++n)
                    acc[m][n] = __builtin_amdgcn_mfma_f32_16x16x32_bf16(
                        af[m], bfr[n], acc[m][n], 0, 0, 0);
        }
    }
    int cr = (lane >> 4) * 4;
    int cc = lane & 15;
    #pragma unroll
    for (int n = 0; n < 4; ++n) {
        int gc = col0 + wn + n * 16 + cc;
        float ps = psq[gc];
        #pragma unroll
        for (int m = 0; m < 4; ++m) {
            int grb = row0 + wm + m * 16 + cr;
            #pragma unroll
            for (int r = 0; r < 4; ++r) {
                float v = 2.0f * acc[m][n][r] - xsq[grb + r] - ps;
                out[(size_t)(grb + r) * NDIM + gc] = v;
            }
        }
    }
}

extern "C" void kernel_launch(void* const* d_in, const int* in_sizes, int n_in,
                              void* d_out, int out_size, void* d_ws, size_t ws_size,
                              hipStream_t stream) {
    const float* X = (const float*)d_in[0];
    const float* P = (const float*)d_in[1];
    float* out = (float*)d_out;

    const size_t bf_elems = (size_t)(MDIM + NDIM) * KDIM;      // 8,912,896
    const size_t need = bf_elems * 2 + (size_t)(MDIM + NDIM) * 4;

    if (ws_size >= need) {
        short* Xbf = (short*)d_ws;
        short* Pbf = Xbf + (size_t)MDIM * KDIM;
        float* xsq = (float*)(Xbf + bf_elems);
        float* psq = xsq + MDIM;
        convert_sumsq<<<(MDIM + NDIM) / 4, 256, 0, stream>>>(X, P, Xbf, Pbf, xsq, psq);
        dist_gemm_bf<<<(MDIM / BM) * (NDIM / BN), 256, 0, stream>>>(Xbf, Pbf, xsq, psq, out);
    } else {
        float* xsq = (float*)d_ws;
        float* psq = xsq + MDIM;
        sumsq_kernel<<<(MDIM + NDIM) / 4, 256, 0, stream>>>(X, P, xsq, psq);
        dist_gemm<<<(MDIM / BM) * (NDIM / BN), 256, 0, stream>>>(X, P, xsq, psq, out);
    }
}

// Round 3
// 40.024 us; speedup vs baseline: 1.3986x; 1.1217x over previous
//
#include <hip/hip_runtime.h>
#include <hip/hip_bf16.h>

#define MDIM 16384
#define NDIM 1024
#define KDIM 512
// fast-path GEMM tile
#define BM 256
#define BN 256
#define BK 64
#define KTILES (KDIM / BK)

typedef __attribute__((ext_vector_type(8))) short bf16x8;
typedef __attribute__((ext_vector_type(4))) float f32x4;

__device__ __forceinline__ short f2bf(float f) {
    union { float f; unsigned u; } v; v.f = f;
    unsigned r = v.u + 0x7fff + ((v.u >> 16) & 1);   // RNE truncate to bf16
    return (short)(r >> 16);
}

__device__ __forceinline__ bf16x8 cvt8(float4 a, float4 b) {
    bf16x8 o;
    o[0] = f2bf(a.x); o[1] = f2bf(a.y); o[2] = f2bf(a.z); o[3] = f2bf(a.w);
    o[4] = f2bf(b.x); o[5] = f2bf(b.y); o[6] = f2bf(b.z); o[7] = f2bf(b.w);
    return o;
}

__device__ __forceinline__ void gload_lds16(const void* g, void* l) {
    __builtin_amdgcn_global_load_lds(
        (const __attribute__((address_space(1))) void*)g,
        (__attribute__((address_space(3))) void*)l, 16, 0, 0);
}

// ---------- fused fp32->bf16 convert + sum-of-squares (one wave per row) ----------
__global__ __launch_bounds__(256) void convert_sumsq(
        const float* __restrict__ X, const float* __restrict__ P,
        short* __restrict__ Xbf, short* __restrict__ Pbf,
        float* __restrict__ xsq, float* __restrict__ psq) {
    int wave = (blockIdx.x * blockDim.x + threadIdx.x) >> 6;
    int lane = threadIdx.x & 63;
    const float* src; short* dstb; float* dsts; int row;
    if (wave < MDIM) { src = X; dstb = Xbf; dsts = xsq; row = wave; }
    else             { src = P; dstb = Pbf; dsts = psq; row = wave - MDIM; }
    const float4* r4 = (const float4*)(src + (size_t)row * KDIM) + lane * 2;
    float4 a = r4[0], b = r4[1];
    *(bf16x8*)(dstb + (size_t)row * KDIM + lane * 8) = cvt8(a, b);
    float s = a.x*a.x + a.y*a.y + a.z*a.z + a.w*a.w
            + b.x*b.x + b.y*b.y + b.z*b.z + b.w*b.w;
    #pragma unroll
    for (int off = 32; off; off >>= 1) s += __shfl_down(s, off, 64);
    if (lane == 0) dsts[row] = s;
}

// ---------- fast path: 256^2 tile, 2-phase double-buffered bf16 GEMM ----------
// Staging via global_load_lds w16, linear LDS dest + pre-XOR'd global source
// (rule #21), XOR-swizzled ds_read (same addressing form as verified R1/R2).
// Prefetch for tile t+1 issued BEFORE compute of tile t; one __syncthreads per
// iteration drains vmcnt and protects buffer reuse.
__global__ __launch_bounds__(512, 2) void dist_gemm_bf2(
        const short* __restrict__ Xbf, const short* __restrict__ Pbf,
        const float* __restrict__ xsq, const float* __restrict__ psq,
        float* __restrict__ out) {
    __shared__ short As[2][BM * BK];   // 2 x 32 KB
    __shared__ short Bs[2][BN * BK];   // 2 x 32 KB

    int tid = threadIdx.x;
    int bid = blockIdx.x;
    // bijective XCD swizzle: nwg = 256, 8 XCDs -> chunks of 32
    int swz = (bid & 7) * 32 + (bid >> 3);
    int bn = swz & 3, bm = swz >> 2;
    int row0 = bm * BM, col0 = bn * BN;

    int lane = tid & 63, wid = tid >> 6;
    int wr = wid >> 2, wc = wid & 3;         // 2(M) x 4(N) wave grid

    f32x4 acc[8][4] = {};

    const short* Ab = Xbf + (size_t)row0 * KDIM;
    const short* Bb = Pbf + (size_t)col0 * KDIM;

    // --- staging: one K-tile (A+B) into buffer sel; 8 gload_lds16/thread ---
    auto stage = [&](int sel, int kt) {
        #pragma unroll
        for (int i = 0; i < 4; ++i) {
            int c = tid + 512 * i;               // 0..2047 16B-chunks
            int row = c >> 3;                    // 0..255
            int g16 = (c & 7) ^ (row & 7);       // pre-swizzled source slot
            const char* ga = (const char*)(Ab + (size_t)row * KDIM)
                             + kt * (BK * 2) + g16 * 16;
            const char* gb = (const char*)(Bb + (size_t)row * KDIM)
                             + kt * (BK * 2) + g16 * 16;
            char* la = (char*)&As[sel][0] + i * 8192 + wid * 1024;  // wave-uniform
            char* lb = (char*)&Bs[sel][0] + i * 8192 + wid * 1024;
            gload_lds16(ga, la);
            gload_lds16(gb, lb);
        }
    };

    // --- compute: one K-tile from buffer sel ---
    auto compute = [&](int sel) {
        #pragma unroll
        for (int ks = 0; ks < 2; ++ks) {
            int kb = ks * 64 + ((lane >> 4) * 16);
            bf16x8 bfr[4];
            #pragma unroll
            for (int n = 0; n < 4; ++n) {
                int row = wc * 64 + n * 16 + (lane & 15);
                int off = (row * (BK * 2) + kb) ^ ((row & 7) << 4);
                bfr[n] = *(const bf16x8*)((const char*)&Bs[sel][0] + off);
            }
            #pragma unroll
            for (int m = 0; m < 8; ++m) {
                int row = wr * 128 + m * 16 + (lane & 15);
                int off = (row * (BK * 2) + kb) ^ ((row & 7) << 4);
                bf16x8 af = *(const bf16x8*)((const char*)&As[sel][0] + off);
                #pragma unroll
                for (int n = 0; n < 4; ++n)
                    acc[m][n] = __builtin_amdgcn_mfma_f32_16x16x32_bf16(
                        af, bfr[n], acc[m][n], 0, 0, 0);
            }
        }
    };

    // prologue
    stage(0, 0);
    __syncthreads();
    int cur = 0;
    for (int kt = 0; kt < KTILES - 1; ++kt) {
        stage(cur ^ 1, kt + 1);      // issue next-tile loads (in flight)
        compute(cur);                // MFMA on current tile
        __syncthreads();             // drains vmcnt -> next tile resident;
                                     // all reads of buf[cur] done
        cur ^= 1;
    }
    compute(cur);                    // last tile

    // epilogue: C/D layout col = lane&15, row = (lane>>4)*4 + reg  [m89]
    int cr = (lane >> 4) * 4;
    int cc = lane & 15;
    float ps[4];
    #pragma unroll
    for (int n = 0; n < 4; ++n) ps[n] = psq[col0 + wc * 64 + n * 16 + cc];
    #pragma unroll
    for (int m = 0; m < 8; ++m) {
        int grb = row0 + wr * 128 + m * 16 + cr;
        #pragma unroll
        for (int r = 0; r < 4; ++r) {
            float xv = xsq[grb + r];
            size_t ob = (size_t)(grb + r) * NDIM;
            #pragma unroll
            for (int n = 0; n < 4; ++n) {
                int gc = col0 + wc * 64 + n * 16 + cc;
                out[ob + gc] = 2.0f * acc[m][n][r] - xv - ps[n];
            }
        }
    }
}

// ---------- fallback path (round-1 kernels, used if ws too small) ----------
__global__ __launch_bounds__(256) void sumsq_kernel(
        const float* __restrict__ X, const float* __restrict__ P,
        float* __restrict__ xsq, float* __restrict__ psq) {
    int wave = (blockIdx.x * blockDim.x + threadIdx.x) >> 6;
    int lane = threadIdx.x & 63;
    const float* src; float* dst; int row;
    if (wave < MDIM) { src = X; dst = xsq; row = wave; }
    else             { src = P; dst = psq; row = wave - MDIM; }
    const float4* r4 = (const float4*)(src + (size_t)row * KDIM) + lane * 2;
    float4 a = r4[0], b = r4[1];
    float s = a.x*a.x + a.y*a.y + a.z*a.z + a.w*a.w
            + b.x*b.x + b.y*b.y + b.z*b.z + b.w*b.w;
    #pragma unroll
    for (int off = 32; off; off >>= 1) s += __shfl_down(s, off, 64);
    if (lane == 0) dst[row] = s;
}

__global__ __launch_bounds__(256) void dist_gemm(
        const float* __restrict__ X, const float* __restrict__ P,
        const float* __restrict__ xsq, const float* __restrict__ psq,
        float* __restrict__ out) {
    __shared__ short As[128 * BK];
    __shared__ short Bs[128 * BK];
    int tid = threadIdx.x;
    int bid = blockIdx.x;
    int swz = (bid & 7) * 128 + (bid >> 3);
    int bn = swz & 7, bm = swz >> 3;
    int row0 = bm * 128, col0 = bn * 128;
    int lane = tid & 63, wid = tid >> 6;
    int wm = (wid >> 1) * 64, wn = (wid & 1) * 64;
    f32x4 acc[4][4] = {};
    int rbase = tid >> 3;
    int kg = tid & 7;
    const float* Abase = X + (size_t)row0 * KDIM;
    const float* Bbase = P + (size_t)col0 * KDIM;
    for (int kt = 0; kt < KDIM / BK; ++kt) {
        int kofs = kt * BK + kg * 8;
        __syncthreads();
        #pragma unroll
        for (int i = 0; i < 4; ++i) {
            int row = rbase + 32 * i;
            const float4* ga = (const float4*)(Abase + (size_t)row * KDIM + kofs);
            float4 a0 = ga[0], a1 = ga[1];
            const float4* gb = (const float4*)(Bbase + (size_t)row * KDIM + kofs);
            float4 b0 = gb[0], b1 = gb[1];
            int off = (row * (BK * 2) + kg * 16) ^ ((row & 7) << 4);
            *(bf16x8*)((char*)As + off) = cvt8(a0, a1);
            *(bf16x8*)((char*)Bs + off) = cvt8(b0, b1);
        }
        __syncthreads();
        #pragma unroll
        for (int ks = 0; ks < 2; ++ks) {
            bf16x8 af[4], bfr[4];
            int kb = ks * 64 + ((lane >> 4) * 16);
            #pragma unroll
            for (int m = 0; m < 4; ++m) {
                int row = wm + m * 16 + (lane & 15);
                int off = (row * (BK * 2) + kb) ^ ((row & 7) << 4);
                af[m] = *(const bf16x8*)((const char*)As + off);
            }
            #pragma unroll
            for (int n = 0; n < 4; ++n) {
                int row = wn + n * 16 + (lane & 15);
                int off = (row * (BK * 2) + kb) ^ ((row & 7) << 4);
                bfr[n] = *(const bf16x8*)((const char*)Bs + off);
            }
            #pragma unroll
            for (int m = 0; m < 4; ++m)
                #pragma unroll
                for (int n = 0; n < 4; ++n)
                    acc[m][n] = __builtin_amdgcn_mfma_f32_16x16x32_bf16(
                        af[m], bfr[n], acc[m][n], 0, 0, 0);
        }
    }
    int cr = (lane >> 4) * 4;
    int cc = lane & 15;
    #pragma unroll
    for (int n = 0; n < 4; ++n) {
        int gc = col0 + wn + n * 16 + cc;
        float ps = psq[gc];
        #pragma unroll
        for (int m = 0; m < 4; ++m) {
            int grb = row0 + wm + m * 16 + cr;
            #pragma unroll
            for (int r = 0; r < 4; ++r) {
                float v = 2.0f * acc[m][n][r] - xsq[grb + r] - ps;
                out[(size_t)(grb + r) * NDIM + gc] = v;
            }
        }
    }
}

extern "C" void kernel_launch(void* const* d_in, const int* in_sizes, int n_in,
                              void* d_out, int out_size, void* d_ws, size_t ws_size,
                              hipStream_t stream) {
    const float* X = (const float*)d_in[0];
    const float* P = (const float*)d_in[1];
    float* out = (float*)d_out;

    const size_t bf_elems = (size_t)(MDIM + NDIM) * KDIM;      // 8,912,896
    const size_t need = bf_elems * 2 + (size_t)(MDIM + NDIM) * 4;

    if (ws_size >= need) {
        short* Xbf = (short*)d_ws;
        short* Pbf = Xbf + (size_t)MDIM * KDIM;
        float* xsq = (float*)(Xbf + bf_elems);
        float* psq = xsq + MDIM;
        convert_sumsq<<<(MDIM + NDIM) / 4, 256, 0, stream>>>(X, P, Xbf, Pbf, xsq, psq);
        dist_gemm_bf2<<<(MDIM / BM) * (NDIM / BN), 512, 0, stream>>>(Xbf, Pbf, xsq, psq, out);
    } else {
        float* xsq = (float*)d_ws;
        float* psq = xsq + MDIM;
        sumsq_kernel<<<(MDIM + NDIM) / 4, 256, 0, stream>>>(X, P, xsq, psq);
        dist_gemm<<<(MDIM / 128) * (NDIM / 128), 256, 0, stream>>>(X, P, xsq, psq, out);
    }
}